// Round 13
// baseline (99.346 us; speedup 1.0000x reference)
//
#include <hip/hip_runtime.h>
#include <math.h>

#define C_IN  128
#define H_IN  56
#define W_IN  56
#define HW_IN (H_IN * W_IN)          // 3136
#define N_IN  8
#define O_MID 64
#define KK    5
#define NCLS  2

// ws layout (floats):
//   [0, 6656)    Weff2[c][52]   slot = (di*5+dj)*2 + k  (50 used, 2 pad; 16B rows)
//   [6656,6658)  beff[2]
//   [8192, ...)  G[p][n][hw][k] : 25*8*3136*2 fl (~5 MB)
#define WROW     52
#define WEFF_FL  (C_IN * WROW)        // 6656
#define BEFF_OFF WEFF_FL
#define G_BASE   8192

// ---------------- k_weff: coalesced fold of O=64 ----------------
// 13 blocks x 256 thr; thread owns flat element e = c*25+p (3200 total).
// Wt[o][c][p] flat = o*3200 + e  -> lane-consecutive loads, fully coalesced.
// Wlin reads are wave-uniform -> scalar cache. Block 12's wave 2 does beff.
__global__ __launch_bounds__(256) void k_weff(const float* __restrict__ Wt,
                                              const float* __restrict__ bias,
                                              const float* __restrict__ Wlin,
                                              const float* __restrict__ blin,
                                              float* __restrict__ ws) {
    const int t = threadIdx.x;
    const int e = blockIdx.x * 256 + t;

    if (e < 3200) {
        float a0 = 0.f, a1 = 0.f;
#pragma unroll 8
        for (int o = 0; o < O_MID; ++o) {
            const float wt = Wt[o * 3200 + e];
            a0 = fmaf(Wlin[o], wt, a0);
            a1 = fmaf(Wlin[64 + o], wt, a1);
        }
        const int c = e / 25;
        const int p = e - c * 25;
        ws[c * WROW + p * 2 + 0] = a0;
        ws[c * WROW + p * 2 + 1] = a1;
    }

    if (blockIdx.x == 12 && t >= 128 && t < 192) {
        const int o = t - 128;
        float v0 = Wlin[o] * bias[o];
        float v1 = Wlin[64 + o] * bias[o];
#pragma unroll
        for (int off = 32; off; off >>= 1) {
            v0 += __shfl_down(v0, off, 64);
            v1 += __shfl_down(v1, off, 64);
        }
        if (o == 0) {
            ws[BEFF_OFF + 0] = v0 + blin[0];
            ws[BEFF_OFF + 1] = v1 + blin[1];
        }
    }
}

// ---------------- k_gemm: in-wave c-split, x once, G once ----------------
// grid (49, 8): 64 px per 256-thr block; wave wv covers px [wv*16, wv*16+16).
// Lane = cgrp*16 + px; step s: c = s*4 + cgrp. W in LDS (padded rows, b128-aligned).
// After shfl reduction all lanes hold the sums; stores distributed over cgrp.
__global__ __launch_bounds__(256) void k_gemm(const float* __restrict__ x,
                                              const float* __restrict__ ws,
                                              float* __restrict__ g) {
    __shared__ float wls[WEFF_FL];        // 26624 B

    const int tid = threadIdx.x;
#pragma unroll
    for (int r = 0; r < 7; ++r) {
        const int i4 = tid + 256 * r;     // float4 index, 1664 total
        if (i4 < WEFF_FL / 4)
            *(float4*)&wls[i4 * 4] = *(const float4*)&ws[i4 * 4];
    }
    __syncthreads();

    const int wv   = tid >> 6;
    const int lane = tid & 63;
    const int cgrp = lane >> 4;
    const int px   = lane & 15;
    const int hw   = blockIdx.x * 64 + wv * 16 + px;
    const int n    = blockIdx.y;

    const float* xc = x + (size_t)n * (C_IN * HW_IN) + hw;

    float acc[50];
#pragma unroll
    for (int i = 0; i < 50; ++i) acc[i] = 0.f;

#pragma unroll 8
    for (int s = 0; s < 32; ++s) {
        const int c = s * 4 + cgrp;
        const float xv = xc[(size_t)c * HW_IN];
        const float* wr = &wls[c * WROW];
#pragma unroll
        for (int i = 0; i < 50; ++i)
            acc[i] = fmaf(xv, wr[i], acc[i]);
    }

    // reduce across cgrp (lane bits 4,5) — all lanes end with the sums
#pragma unroll
    for (int i = 0; i < 50; ++i) {
        float v = acc[i];
        v += __shfl_xor(v, 16, 64);
        v += __shfl_xor(v, 32, 64);
        acc[i] = v;
    }

    // distributed store: cgrp g stores p = g, g+4, ... (7/6/6/6)
#pragma unroll
    for (int p25 = 0; p25 < 7; ++p25) {
        const int p = p25 * 4 + cgrp;
        if (p < 25) {
            const size_t idx = (((size_t)p * N_IN + n) * HW_IN + hw) * 2;
            *(float2*)&g[idx] = make_float2(acc[p * 2 + 0], acc[p * 2 + 1]);
        }
    }
}

// ---------------- k_final: gather shifted G, abs-stats, output ----------------
// grid (49, 8), 128 thr. lane: px = tid>>1 (64 px/block), k = tid&1.
__global__ __launch_bounds__(128) void k_final(const float* __restrict__ ws,
                                               const float* __restrict__ g,
                                               float* __restrict__ out) {
    const int tid = threadIdx.x;
    const int px  = tid >> 1;
    const int k   = tid & 1;
    const int hw  = blockIdx.x * 64 + px;
    const int n   = blockIdx.y;
    const int y   = hw / W_IN;
    const int x   = hw - y * W_IN;

    const float be = ws[BEFF_OFF + k];

    float A = 0.f, X = 0.f, Y = 0.f, Cs = 0.f;

#pragma unroll
    for (int di = 0; di < 5; ++di) {
        const int yy = y + di - 2;
        const bool rowok = (unsigned)yy < H_IN;
        const float fdi = (float)(di - 2);
#pragma unroll
        for (int dj = 0; dj < 5; ++dj) {
            const int xx = x + dj - 2;
            const bool ok = rowok && ((unsigned)xx < W_IN);
            float v = 0.f;
            if (ok) {
                const int p = di * 5 + dj;
                v = g[(((size_t)p * N_IN + n) * HW_IN + yy * W_IN + xx) * 2 + k];
            }
            v += be;
            const float a = fabsf(v);
            const float fdj = (float)(dj - 2);
            A += a; X = fmaf(a, fdj, X); Y = fmaf(a, fdi, Y); Cs += v;
        }
    }

    const float xd = X / A, yd = Y / A;
    const float o = Cs * expf(-0.5f * sqrtf(xd * xd + yd * yd));
    out[((size_t)n * HW_IN + hw) * 2 + k] = o;
}

extern "C" void kernel_launch(void* const* d_in, const int* in_sizes, int n_in,
                              void* d_out, int out_size, void* d_ws, size_t ws_size,
                              hipStream_t stream) {
    const float* x    = (const float*)d_in[0];
    const float* Wt   = (const float*)d_in[1];
    const float* bias = (const float*)d_in[2];
    const float* Wlin = (const float*)d_in[3];
    const float* blin = (const float*)d_in[4];
    float* ws = (float*)d_ws;

    k_weff<<<dim3(13), dim3(256), 0, stream>>>(Wt, bias, Wlin, blin, ws);
    k_gemm<<<dim3(49, N_IN), dim3(256), 0, stream>>>(x, ws, ws + G_BASE);
    k_final<<<dim3(49, N_IN), dim3(128), 0, stream>>>(ws, ws + G_BASE, (float*)d_out);
}

// Round 14
// 88.701 us; speedup vs baseline: 1.1200x; 1.1200x over previous
//
#include <hip/hip_runtime.h>
#include <math.h>

#define C_IN  128
#define H_IN  56
#define W_IN  56
#define HW_IN (H_IN * W_IN)          // 3136
#define N_IN  8
#define O_MID 64
#define KK    5
#define NCLS  2

// ws layout (floats):
//   [0, 6656)    Weff2[c][52]   slot = (di*5+dj)*2 + k  (50 used, 2 pad; 16B rows)
//   [6656,6658)  beff[2]
//   [8192, ...)  G[p][n][hw][k] : 25*8*3136*2 fl (~5 MB)
#define WROW     52
#define WEFF_FL  (C_IN * WROW)        // 6656
#define BEFF_OFF WEFF_FL
#define G_BASE   8192

// ---------------- k_weff: coalesced fold of O=64 ----------------
// 13 blocks x 256 thr; thread owns flat element e = c*25+p (3200 total).
// Wt[o][c][p] flat = o*3200 + e  -> lane-consecutive loads, fully coalesced.
// Wlin reads are wave-uniform -> scalar cache. Block 12's wave 2 does beff.
__global__ __launch_bounds__(256) void k_weff(const float* __restrict__ Wt,
                                              const float* __restrict__ bias,
                                              const float* __restrict__ Wlin,
                                              const float* __restrict__ blin,
                                              float* __restrict__ ws) {
    const int t = threadIdx.x;
    const int e = blockIdx.x * 256 + t;

    if (e < 3200) {
        float a0 = 0.f, a1 = 0.f;
#pragma unroll 8
        for (int o = 0; o < O_MID; ++o) {
            const float wt = Wt[o * 3200 + e];
            a0 = fmaf(Wlin[o], wt, a0);
            a1 = fmaf(Wlin[64 + o], wt, a1);
        }
        const int c = e / 25;
        const int p = e - c * 25;
        ws[c * WROW + p * 2 + 0] = a0;
        ws[c * WROW + p * 2 + 1] = a1;
    }

    if (blockIdx.x == 12 && t >= 128 && t < 192) {
        const int o = t - 128;
        float v0 = Wlin[o] * bias[o];
        float v1 = Wlin[64 + o] * bias[o];
#pragma unroll
        for (int off = 32; off; off >>= 1) {
            v0 += __shfl_down(v0, off, 64);
            v1 += __shfl_down(v1, off, 64);
        }
        if (o == 0) {
            ws[BEFF_OFF + 0] = v0 + blin[0];
            ws[BEFF_OFF + 1] = v1 + blin[1];
        }
    }
}

// ---------------- k_gemm: in-wave c-split, x once, G once ----------------
// grid (49, 8): 64 px per 256-thr block; wave wv covers px [wv*16, wv*16+16).
// Lane = cgrp*16 + px; step s: c = s*4 + cgrp. W in LDS (padded rows, b128-aligned).
// NOTE (R13 lesson): keep the exec-masked cgrp==0 stores — each store hits ONE
// contiguous 128B segment. Distributing stores over cgrp made every store
// instruction scatter to 4 planes 200KB apart and cost ~10us.
__global__ __launch_bounds__(256) void k_gemm(const float* __restrict__ x,
                                              const float* __restrict__ ws,
                                              float* __restrict__ g) {
    __shared__ float wls[WEFF_FL];        // 26624 B

    const int tid = threadIdx.x;
#pragma unroll
    for (int r = 0; r < 7; ++r) {
        const int i4 = tid + 256 * r;     // float4 index, 1664 total
        if (i4 < WEFF_FL / 4)
            *(float4*)&wls[i4 * 4] = *(const float4*)&ws[i4 * 4];
    }
    __syncthreads();

    const int wv   = tid >> 6;
    const int lane = tid & 63;
    const int cgrp = lane >> 4;
    const int px   = lane & 15;
    const int hw   = blockIdx.x * 64 + wv * 16 + px;
    const int n    = blockIdx.y;

    const float* xc = x + (size_t)n * (C_IN * HW_IN) + hw;

    float acc[50];
#pragma unroll
    for (int i = 0; i < 50; ++i) acc[i] = 0.f;

#pragma unroll 8
    for (int s = 0; s < 32; ++s) {
        const int c = s * 4 + cgrp;
        const float xv = xc[(size_t)c * HW_IN];
        const float* wr = &wls[c * WROW];
#pragma unroll
        for (int i = 0; i < 50; ++i)
            acc[i] = fmaf(xv, wr[i], acc[i]);
    }

    // reduce across cgrp (lane bits 4,5)
#pragma unroll
    for (int i = 0; i < 50; ++i) {
        float v = acc[i];
        v += __shfl_xor(v, 16, 64);
        v += __shfl_xor(v, 32, 64);
        acc[i] = v;
    }

    if (cgrp == 0) {
#pragma unroll
        for (int p = 0; p < 25; ++p) {
            const size_t idx = (((size_t)p * N_IN + n) * HW_IN + hw) * 2;
            *(float2*)&g[idx] = make_float2(acc[p * 2 + 0], acc[p * 2 + 1]);
        }
    }
}

// ---------------- k_final: gather shifted G, abs-stats, output ----------------
// grid (49, 8), 128 thr. lane: px = tid>>1 (64 px/block), k = tid&1.
__global__ __launch_bounds__(128) void k_final(const float* __restrict__ ws,
                                               const float* __restrict__ g,
                                               float* __restrict__ out) {
    const int tid = threadIdx.x;
    const int px  = tid >> 1;
    const int k   = tid & 1;
    const int hw  = blockIdx.x * 64 + px;
    const int n   = blockIdx.y;
    const int y   = hw / W_IN;
    const int x   = hw - y * W_IN;

    const float be = ws[BEFF_OFF + k];

    float A = 0.f, X = 0.f, Y = 0.f, Cs = 0.f;

#pragma unroll
    for (int di = 0; di < 5; ++di) {
        const int yy = y + di - 2;
        const bool rowok = (unsigned)yy < H_IN;
        const float fdi = (float)(di - 2);
#pragma unroll
        for (int dj = 0; dj < 5; ++dj) {
            const int xx = x + dj - 2;
            const bool ok = rowok && ((unsigned)xx < W_IN);
            float v = 0.f;
            if (ok) {
                const int p = di * 5 + dj;
                v = g[(((size_t)p * N_IN + n) * HW_IN + yy * W_IN + xx) * 2 + k];
            }
            v += be;
            const float a = fabsf(v);
            const float fdj = (float)(dj - 2);
            A += a; X = fmaf(a, fdj, X); Y = fmaf(a, fdi, Y); Cs += v;
        }
    }

    const float xd = X / A, yd = Y / A;
    const float o = Cs * expf(-0.5f * sqrtf(xd * xd + yd * yd));
    out[((size_t)n * HW_IN + hw) * 2 + k] = o;
}

extern "C" void kernel_launch(void* const* d_in, const int* in_sizes, int n_in,
                              void* d_out, int out_size, void* d_ws, size_t ws_size,
                              hipStream_t stream) {
    const float* x    = (const float*)d_in[0];
    const float* Wt   = (const float*)d_in[1];
    const float* bias = (const float*)d_in[2];
    const float* Wlin = (const float*)d_in[3];
    const float* blin = (const float*)d_in[4];
    float* ws = (float*)d_ws;

    k_weff<<<dim3(13), dim3(256), 0, stream>>>(Wt, bias, Wlin, blin, ws);
    k_gemm<<<dim3(49, N_IN), dim3(256), 0, stream>>>(x, ws, ws + G_BASE);
    k_final<<<dim3(49, N_IN), dim3(128), 0, stream>>>(ws, ws + G_BASE, (float*)d_out);
}